// Round 3
// baseline (27.943 us; speedup 1.0000x reference)
//
#include <hip/hip_runtime.h>

namespace {

constexpr int T = 64;
constexpr int B = 65536;
constexpr int C = 32;
constexpr int NT = 6;
constexpr int PER = 4;       // channels per thread -> 8 threads per sequence
constexpr int BLOCK = 256;
constexpr int D = 8;         // global prefetch depth in steps
constexpr int SW = 40;       // f32 words per LDS column (160 B stride)
// LDS column j holds channels 0..31 at words [j*40, j*40+32). Thread p (gid&7)
// reads one float4 at byte col*160 + p*16. Bank-start = (8*col + 4*p) mod 32:
// col staggers by 8 banks, p by 4 -> same-bank different-address aliasing is
// ~2-way (free on CDNA4); same (col,p) across lanes broadcasts.

__global__ __launch_bounds__(BLOCK, 8) void trust_kernel(
    const int2* __restrict__ perf,    // [T*B] (x = failure, y = success)
    const int*  __restrict__ obsids,  // [T*B]
    const int*  __restrict__ predids, // [B]
    const float* __restrict__ obsM,   // [C*NT] row-major [C][NT]
    float* __restrict__ out)          // [B]
{
    __shared__ float lobs[NT * SW];
    const int tid = threadIdx.x;
    if (tid < NT * SW) {              // 240 < 256: single pass
        const int j = tid / SW;
        const int w = tid - j * SW;
        lobs[tid] = (w < C) ? obsM[w * NT + j] : 0.0f;
    }
    __syncthreads();

    const int gid = blockIdx.x * BLOCK + tid;
    const int b   = gid >> 3;         // sequence index
    const int p   = gid & 7;          // which 4 channels this thread owns
    const int pb  = p * 16;           // byte offset within a column
    const char* lb = (const char*)lobs;

    const float PINF = __builtin_inff();
    const float NINF = -PINF;

    float m0 = 0.0f, m1 = 0.0f, m2 = 0.0f, m3 = 0.0f;

    const int2* pfp = perf + b;
    const int*  idp = obsids + b;

    // D-deep raw prefetch buffers (statically indexed everywhere)
    int2 pfb[D];
    int  idb[D];
#pragma unroll
    for (int d = 0; d < D; ++d) {
        pfb[d] = pfp[d * B];
        idb[d] = idp[d * B];
    }

    // One fold step (1 med3 per channel):
    //   success (y): aa=+INF -> med3(m,+INF,cap) = max(m,cap)
    //   failure (x): aa=-INF -> med3(m,-INF,cap) = min(m,cap)
    //   noop: exec-masked off (no LDS traffic, mean unchanged)
#define CONSUME(d_)                                                         \
    do {                                                                    \
        const int  px_  = pfb[d_].x, py_ = pfb[d_].y;                       \
        const bool act_ = (px_ | py_) != 0;                                 \
        const float aa_ = (px_ != 0) ? NINF : PINF;                         \
        const int  adr_ = idb[d_] * 160 + pb;                               \
        if (act_) {                                                         \
            const float4 c4_ = *(const float4*)(lb + adr_);                 \
            m0 = __builtin_amdgcn_fmed3f(m0, aa_, c4_.x);                   \
            m1 = __builtin_amdgcn_fmed3f(m1, aa_, c4_.y);                   \
            m2 = __builtin_amdgcn_fmed3f(m2, aa_, c4_.z);                   \
            m3 = __builtin_amdgcn_fmed3f(m3, aa_, c4_.w);                   \
        }                                                                   \
    } while (0)

    for (int tb = 0; tb < T - D; tb += D) {
#pragma unroll
        for (int d = 0; d < D; ++d) {
            // issue prefetch for step tb + D + d (raw; converted D steps later)
            const int2 pfn = pfp[(tb + D + d) * B];
            const int  idn = idp[(tb + D + d) * B];
            CONSUME(d);
            pfb[d] = pfn;
            idb[d] = idn;
        }
    }
    // epilogue: last D steps
#pragma unroll
    for (int d = 0; d < D; ++d) {
        CONSUME(d);
    }
#undef CONSUME

    // trust predicate over this thread's 4 channels
    const int pid = predids[b];
    const float4 rq = *(const float4*)(lb + pid * 160 + pb);
    const bool ok = (rq.x <= m0) & (rq.y <= m1) & (rq.z <= m2) & (rq.w <= m3);

    // combine the 8 threads of each b (lanes 8k..8k+7 of the same wave)
    const unsigned long long bal = __ballot(ok);
    const int lane = tid & 63;
    const int grp  = lane & ~7;
    if (p == 0) {
        out[b] = (((bal >> grp) & 0xFFull) == 0xFFull) ? 1.0f : 0.0f;
    }
}

}  // namespace

extern "C" void kernel_launch(void* const* d_in, const int* in_sizes, int n_in,
                              void* d_out, int out_size, void* d_ws, size_t ws_size,
                              hipStream_t stream) {
    const int2*  perf    = (const int2*)d_in[0];   // inptasksperf [T,B,2] int32
    const int*   obsids  = (const int*)d_in[1];    // tasksobsids  [T,B,1] int32
    const int*   predids = (const int*)d_in[2];    // taskspredids [B,1]   int32
    const float* obsM    = (const float*)d_in[3];  // obsMatrix    [C,NT]  f32
    float*       out     = (float*)d_out;          // trust        [B,1]   f32

    const int total_threads = 8 * B;               // 8 threads per sequence
    dim3 grid(total_threads / BLOCK), block(BLOCK);
    trust_kernel<<<grid, block, 0, stream>>>(perf, obsids, predids, obsM, out);
}

// Round 4
// 17.658 us; speedup vs baseline: 1.5824x; 1.5824x over previous
//
#include <hip/hip_runtime.h>

namespace {

constexpr int T = 64;
constexpr int B = 65536;
constexpr int C = 32;
constexpr int NT = 6;
constexpr int WAVES = 4;           // waves per block
constexpr int BLOCK = WAVES * 64;  // 256 threads
constexpr int CHUNK = T / WAVES;   // 16 time-steps per wave
constexpr int QS = 8;              // u32 stride per id-row of Q table

// Algebra: per sequence b with prediction column pid, track W (bit c =
// "M[c,pid] <= mean[c]"). Success step id: W |= Q[id]; failure: W &= Q[id];
// noop: unchanged, where Q[id] bit c = (M[c,pid] <= M[c,id]). Each step is an
// affine boolean map W -> (W & A) | Bv, which composes associatively:
//   (a1,b1) then (a2,b2)  ==  (a1&a2, (b1&a2)|b2)
// so waves fold disjoint time-chunks and combine in order at the end.
__global__ __launch_bounds__(BLOCK) void trust_kernel(
    const int2* __restrict__ perf,    // [T*B] (x = failure, y = success)
    const int*  __restrict__ obsids,  // [T*B]
    const int*  __restrict__ predids, // [B]
    const float* __restrict__ obsM,   // [C*NT] row-major [C][NT]
    float* __restrict__ out)          // [B]
{
    __shared__ float    MT[NT * C];      // MT[j*32+c] = M[c][j]
    __shared__ unsigned Qtab[7 * QS];    // Qtab[id*QS+pid]; row id==6 is pass(0)
    __shared__ unsigned sa[WAVES][64], sb[WAVES][64];

    const int tid  = threadIdx.x;
    const int lane = tid & 63;
    const int w    = tid >> 6;

    if (tid < C * NT) {
        const int c = tid / NT, j = tid - c * NT;
        MT[j * C + c] = obsM[tid];
    }
    __syncthreads();

    // Build Q: 42 entries (id 0..6 x pid 0..5), two per ballot (half-waves).
    {
        const int half = lane >> 5;
        const int c    = lane & 31;
        for (int k = w; k <= 20; k += WAVES) {
            const int e   = 2 * k + half;       // entry index 0..41
            const int id  = e / 6;
            const int pid = e - id * 6;
            const float val = (id < 6) ? MT[id * C + c] : 0.0f;  // id 6 => mean=0
            const float req = MT[pid * C + c];
            const unsigned long long bal = __ballot(req <= val);
            if (c == 0) {
                Qtab[id * QS + pid] =
                    (unsigned)(half ? (bal >> 32) : (bal & 0xFFFFFFFFull));
            }
        }
    }
    __syncthreads();

    const int b   = blockIdx.x * 64 + lane;
    const int pid = predids[b];

    // Load this wave's CHUNK raw steps (fully unrolled, static indexing).
    int2 pf[CHUNK];
    int  id[CHUNK];
    const int tbase = w * CHUNK;
#pragma unroll
    for (int k = 0; k < CHUNK; ++k) {
        pf[k] = perf[(tbase + k) * B + b];
        id[k] = obsids[(tbase + k) * B + b];
    }

    unsigned a = 0xFFFFFFFFu, bb = 0u;
#pragma unroll
    for (int k = 0; k < CHUNK; ++k) {
        const unsigned Q  = Qtab[id[k] * QS + pid];
        const unsigned A  = (pf[k].x != 0) ? Q : 0xFFFFFFFFu;  // failure: &= Q
        const unsigned Bv = (pf[k].y != 0) ? Q : 0u;           // success: |= Q
        a  = a & A;
        bb = (bb & A) | Bv;
    }
    sa[w][lane] = a;
    sb[w][lane] = bb;
    __syncthreads();

    // Combine the 4 chunks in time order; apply to W_init = pass(0).
    if (tid < 64) {
        unsigned ca = sa[0][lane], cb = sb[0][lane];
#pragma unroll
        for (int wv = 1; wv < WAVES; ++wv) {
            const unsigned a2 = sa[wv][lane], b2 = sb[wv][lane];
            cb = (cb & a2) | b2;
            ca = ca & a2;
        }
        const unsigned Winit = Qtab[6 * QS + pid];   // bit c = (M[c,pid] <= 0)
        const unsigned W = (Winit & ca) | cb;
        out[b] = (W == 0xFFFFFFFFu) ? 1.0f : 0.0f;
    }
}

}  // namespace

extern "C" void kernel_launch(void* const* d_in, const int* in_sizes, int n_in,
                              void* d_out, int out_size, void* d_ws, size_t ws_size,
                              hipStream_t stream) {
    const int2*  perf    = (const int2*)d_in[0];   // inptasksperf [T,B,2] int32
    const int*   obsids  = (const int*)d_in[1];    // tasksobsids  [T,B,1] int32
    const int*   predids = (const int*)d_in[2];    // taskspredids [B,1]   int32
    const float* obsM    = (const float*)d_in[3];  // obsMatrix    [C,NT]  f32
    float*       out     = (float*)d_out;          // trust        [B,1]   f32

    dim3 grid(B / 64), block(BLOCK);               // 1024 blocks x 256 threads
    trust_kernel<<<grid, block, 0, stream>>>(perf, obsids, predids, obsM, out);
}

// Round 5
// 17.239 us; speedup vs baseline: 1.6209x; 1.0243x over previous
//
#include <hip/hip_runtime.h>

namespace {

constexpr int T = 64;
constexpr int B = 65536;
constexpr int C = 32;
constexpr int NT = 6;
constexpr int WAVES = 8;           // waves per block
constexpr int BLOCK = WAVES * 64;  // 512 threads
constexpr int CHUNK = T / WAVES;   // 8 time-steps per wave
constexpr int QS = 8;              // u32 stride per id-row of Q table

// Algebra: per sequence b with prediction column pid, track W (bit c =
// "M[c,pid] <= mean[c]"). Success step id: W |= Q[id]; failure: W &= Q[id];
// noop: unchanged, where Q[id] bit c = (M[c,pid] <= M[c,id]). Each step is an
// affine boolean map W -> (W & A) | Bv, which composes associatively:
//   (a1,b1) then (a2,b2)  ==  (a1&a2, (b1&a2)|b2)
// so waves fold disjoint time-chunks and combine in order at the end.
__global__ __launch_bounds__(BLOCK, 6) void trust_kernel(
    const int2* __restrict__ perf,    // [T*B] (x = failure, y = success)
    const int*  __restrict__ obsids,  // [T*B]
    const int*  __restrict__ predids, // [B]
    const float* __restrict__ obsM,   // [C*NT] row-major [C][NT]
    float* __restrict__ out)          // [B]
{
    __shared__ float    MT[NT * C];      // MT[j*32+c] = M[c][j]
    __shared__ unsigned Qtab[7 * QS];    // Qtab[id*QS+pid]; row id==6 is t=0 state
    __shared__ unsigned sa[WAVES][64], sb[WAVES][64];

    const int tid  = threadIdx.x;
    const int lane = tid & 63;
    const int w    = tid >> 6;

    if (tid < C * NT) {
        const int c = tid / NT, j = tid - c * NT;
        MT[j * C + c] = obsM[tid];
    }
    __syncthreads();

    // Build Q: 42 entries (id 0..6 x pid 0..5), two per ballot (half-waves).
    {
        const int half = lane >> 5;
        const int c    = lane & 31;
        for (int k = w; k <= 20; k += WAVES) {
            const int e   = 2 * k + half;       // entry index 0..41
            const int id  = e / 6;
            const int pid = e - id * 6;
            const float val = (id < 6) ? MT[id * C + c] : 0.0f;  // id 6 => mean=0
            const float req = MT[pid * C + c];
            const unsigned long long bal = __ballot(req <= val);
            if (c == 0) {
                Qtab[id * QS + pid] =
                    (unsigned)(half ? (bal >> 32) : (bal & 0xFFFFFFFFull));
            }
        }
    }
    __syncthreads();

    const int b   = blockIdx.x * 64 + lane;
    const int pid = predids[b];

    // Load this wave's CHUNK raw steps (fully unrolled, static indexing).
    int2 pf[CHUNK];
    int  id[CHUNK];
    const int tbase = w * CHUNK;
#pragma unroll
    for (int k = 0; k < CHUNK; ++k) {
        pf[k] = perf[(tbase + k) * B + b];
        id[k] = obsids[(tbase + k) * B + b];
    }

    unsigned a = 0xFFFFFFFFu, bb = 0u;
#pragma unroll
    for (int k = 0; k < CHUNK; ++k) {
        const unsigned Q  = Qtab[id[k] * QS + pid];
        const unsigned A  = (pf[k].x != 0) ? Q : 0xFFFFFFFFu;  // failure: &= Q
        const unsigned Bv = (pf[k].y != 0) ? Q : 0u;           // success: |= Q
        a  = a & A;
        bb = (bb & A) | Bv;
    }
    sa[w][lane] = a;
    sb[w][lane] = bb;
    __syncthreads();

    // Combine the 8 chunks in time order; apply to W_init.
    if (tid < 64) {
        unsigned ca = sa[0][lane], cb = sb[0][lane];
#pragma unroll
        for (int wv = 1; wv < WAVES; ++wv) {
            const unsigned a2 = sa[wv][lane], b2 = sb[wv][lane];
            cb = (cb & a2) | b2;
            ca = ca & a2;
        }
        const unsigned Winit = Qtab[6 * QS + pid];   // bit c = (M[c,pid] <= 0)
        const unsigned W = (Winit & ca) | cb;
        out[b] = (W == 0xFFFFFFFFu) ? 1.0f : 0.0f;
    }
}

}  // namespace

extern "C" void kernel_launch(void* const* d_in, const int* in_sizes, int n_in,
                              void* d_out, int out_size, void* d_ws, size_t ws_size,
                              hipStream_t stream) {
    const int2*  perf    = (const int2*)d_in[0];   // inptasksperf [T,B,2] int32
    const int*   obsids  = (const int*)d_in[1];    // tasksobsids  [T,B,1] int32
    const int*   predids = (const int*)d_in[2];    // taskspredids [B,1]   int32
    const float* obsM    = (const float*)d_in[3];  // obsMatrix    [C,NT]  f32
    float*       out     = (float*)d_out;          // trust        [B,1]   f32

    dim3 grid(B / 64), block(BLOCK);               // 1024 blocks x 512 threads
    trust_kernel<<<grid, block, 0, stream>>>(perf, obsids, predids, obsM, out);
}

// Round 6
// 16.119 us; speedup vs baseline: 1.7336x; 1.0695x over previous
//
#include <hip/hip_runtime.h>

namespace {

constexpr int T = 64;
constexpr int B = 65536;
constexpr int C = 32;
constexpr int NT = 6;
constexpr int WAVES = 8;            // waves per block
constexpr int BLOCK = WAVES * 64;   // 512 threads
constexpr int CHUNK = T / WAVES;    // 8 time-steps per wave
constexpr int SEQS = 256;           // sequences per block (4 per lane)
constexpr int QS = 8;               // u32 stride per id-row of Q table

// Algebra (validated R3/R4): per sequence b with prediction column pid, track
// W (bit c = "M[c,pid] <= mean[c]"). Success id: W |= Q[id]; failure:
// W &= Q[id]; noop unchanged, where Q[id] bit c = (M[c,pid] <= M[c,id]).
// Steps are affine boolean maps W -> (W & A) | Bv, composing associatively:
//   (a1,b1) then (a2,b2) == (a1&a2, (b1&a2)|b2)
// Waves fold disjoint t-chunks; combine in t-order at the end.
__global__ __launch_bounds__(BLOCK) void trust_kernel(
    const int2* __restrict__ perf,    // [T*B] (x = failure, y = success)
    const int*  __restrict__ obsids,  // [T*B]
    const int*  __restrict__ predids, // [B]
    const float* __restrict__ obsM,   // [C*NT] row-major [C][NT]
    float* __restrict__ out)          // [B]
{
    __shared__ float    MT[NT * C];     // MT[j*32+c] = M[c][j]
    __shared__ unsigned Qtab[7 * QS];   // row id==6 encodes the t=0 state
    __shared__ uint2    sab[WAVES][SEQS];  // per-chunk (a,b) per sequence

    const int tid  = threadIdx.x;
    const int lane = tid & 63;
    const int w    = tid >> 6;

    // ---- prologue: build Q table (once, ~0.3us), before load issue ----
    if (tid < C * NT) {
        const int c = tid / NT, j = tid - c * NT;
        MT[j * C + c] = obsM[tid];
    }
    __syncthreads();
    {
        const int half = lane >> 5;
        const int c    = lane & 31;
        for (int k = w; k <= 20; k += WAVES) {
            const int e   = 2 * k + half;     // entry 0..41
            const int id  = e / 6;
            const int pid = e - id * 6;
            const float val = (id < 6) ? MT[id * C + c] : 0.0f;  // id6 => mean=0
            const float req = MT[pid * C + c];
            const unsigned long long bal = __ballot(req <= val);
            if (c == 0) {
                Qtab[id * QS + pid] =
                    (unsigned)(half ? (bal >> 32) : (bal & 0xFFFFFFFFull));
            }
        }
    }
    __syncthreads();

    // ---- fat-load phase: 4 sequences per lane, int4 (1KB/wave) requests ----
    const int sbase = blockIdx.x * SEQS;      // block's first sequence
    const int tb    = w * CHUNK;              // wave's first time-step

    int4 pfA[CHUNK], pfB[CHUNK], idv[CHUNK];
#pragma unroll
    for (int k = 0; k < CHUNK; ++k) {
        const int e = (tb + k) * B + sbase;   // int2-element index
        pfA[k] = ((const int4*)perf)[(e >> 1) + 2 * lane];      // seqs 4l,4l+1
        pfB[k] = ((const int4*)perf)[(e >> 1) + 2 * lane + 1];  // seqs 4l+2,4l+3
        idv[k] = ((const int4*)obsids)[(e >> 2) + lane];        // 4 ids
    }
    const int4 pid4 = ((const int4*)predids)[(sbase >> 2) + lane];

    unsigned a0 = ~0u, b0 = 0u, a1 = ~0u, b1 = 0u;
    unsigned a2 = ~0u, b2 = 0u, a3 = ~0u, b3 = 0u;

#define STEP(px, py, idq, pidq, aA, bB)                                     \
    do {                                                                    \
        const unsigned Q_  = Qtab[(idq) * QS + (pidq)];                     \
        const unsigned A_  = ((px) != 0) ? Q_ : 0xFFFFFFFFu;                \
        const unsigned Bv_ = ((py) != 0) ? Q_ : 0u;                         \
        aA = aA & A_;                                                       \
        bB = (bB & A_) | Bv_;                                               \
    } while (0)

#pragma unroll
    for (int k = 0; k < CHUNK; ++k) {
        STEP(pfA[k].x, pfA[k].y, idv[k].x, pid4.x, a0, b0);
        STEP(pfA[k].z, pfA[k].w, idv[k].y, pid4.y, a1, b1);
        STEP(pfB[k].x, pfB[k].y, idv[k].z, pid4.z, a2, b2);
        STEP(pfB[k].z, pfB[k].w, idv[k].w, pid4.w, a3, b3);
    }
#undef STEP

    const int s0 = 4 * lane;
    sab[w][s0 + 0] = make_uint2(a0, b0);
    sab[w][s0 + 1] = make_uint2(a1, b1);
    sab[w][s0 + 2] = make_uint2(a2, b2);
    sab[w][s0 + 3] = make_uint2(a3, b3);
    __syncthreads();

    // ---- combine 8 chunks in t order; one thread per sequence ----
    if (tid < SEQS) {
        uint2 c0 = sab[0][tid];
        unsigned ca = c0.x, cb = c0.y;
#pragma unroll
        for (int wv = 1; wv < WAVES; ++wv) {
            const uint2 c2 = sab[wv][tid];
            cb = (cb & c2.x) | c2.y;
            ca = ca & c2.x;
        }
        const int pid = predids[sbase + tid];
        const unsigned Winit = Qtab[6 * QS + pid];  // bit c = (M[c,pid] <= 0)
        const unsigned W = (Winit & ca) | cb;
        out[sbase + tid] = (W == 0xFFFFFFFFu) ? 1.0f : 0.0f;
    }
}

}  // namespace

extern "C" void kernel_launch(void* const* d_in, const int* in_sizes, int n_in,
                              void* d_out, int out_size, void* d_ws, size_t ws_size,
                              hipStream_t stream) {
    const int2*  perf    = (const int2*)d_in[0];   // inptasksperf [T,B,2] int32
    const int*   obsids  = (const int*)d_in[1];    // tasksobsids  [T,B,1] int32
    const int*   predids = (const int*)d_in[2];    // taskspredids [B,1]   int32
    const float* obsM    = (const float*)d_in[3];  // obsMatrix    [C,NT]  f32
    float*       out     = (float*)d_out;          // trust        [B,1]   f32

    dim3 grid(B / SEQS), block(BLOCK);             // 256 blocks x 512 threads
    trust_kernel<<<grid, block, 0, stream>>>(perf, obsids, predids, obsM, out);
}

// Round 8
// 14.057 us; speedup vs baseline: 1.9878x; 1.1467x over previous
//
#include <hip/hip_runtime.h>

namespace {

constexpr int T = 64;
constexpr int B = 65536;
constexpr int C = 32;
constexpr int NT = 6;
constexpr int WAVES = 8;            // waves per block
constexpr int BLOCK = WAVES * 64;   // 512 threads
constexpr int CHUNK = T / WAVES;    // 8 time-steps per wave
constexpr int SEQS = 256;           // sequences per block (4 per lane)
constexpr int QS = 8;               // u32 stride per id-row of Q table

typedef int v4i __attribute__((ext_vector_type(4)));  // nt-builtin-compatible

// Algebra (validated R3-R5): per sequence b with prediction column pid, track
// W (bit c = "M[c,pid] <= mean[c]"). Success id: W |= Q[id]; failure:
// W &= Q[id]; noop unchanged, where Q[id] bit c = (M[c,pid] <= M[c,id]).
// Steps are affine boolean maps W -> (W & A) | Bv, composing associatively:
//   (a1,b1) then (a2,b2) == (a1&a2, (b1&a2)|b2)
// Waves fold disjoint t-chunks; combine in t-order at the end.
//
// All global traffic is NON-TEMPORAL: the harness's per-replay 268MB fill
// leaves the 256MB L3 full of dirty lines; normal loads would allocate and
// force a 64B writeback per 64B read (2x HBM traffic - the measured 16us
// floor). nt loads stream past L3 without displacing dirty data.
__global__ __launch_bounds__(BLOCK) void trust_kernel(
    const int2* __restrict__ perf,    // [T*B] (x = failure, y = success)
    const int*  __restrict__ obsids,  // [T*B]
    const int*  __restrict__ predids, // [B]
    const float* __restrict__ obsM,   // [C*NT] row-major [C][NT]
    float* __restrict__ out)          // [B]
{
    __shared__ float    MT[NT * C];     // MT[j*32+c] = M[c][j]
    __shared__ unsigned Qtab[7 * QS];   // row id==6 encodes the t=0 state
    __shared__ uint2    sab[WAVES][SEQS];  // per-chunk (a,b) per sequence

    const int tid  = threadIdx.x;
    const int lane = tid & 63;
    const int w    = tid >> 6;

    // ---- prologue: build Q table (once), before load issue ----
    if (tid < C * NT) {
        const int c = tid / NT, j = tid - c * NT;
        MT[j * C + c] = obsM[tid];
    }
    __syncthreads();
    {
        const int half = lane >> 5;
        const int c    = lane & 31;
        for (int k = w; k <= 20; k += WAVES) {
            const int e   = 2 * k + half;     // entry 0..41
            const int id  = e / 6;
            const int pid = e - id * 6;
            const float val = (id < 6) ? MT[id * C + c] : 0.0f;  // id6 => mean=0
            const float req = MT[pid * C + c];
            const unsigned long long bal = __ballot(req <= val);
            if (c == 0) {
                Qtab[id * QS + pid] =
                    (unsigned)(half ? (bal >> 32) : (bal & 0xFFFFFFFFull));
            }
        }
    }
    __syncthreads();

    // ---- fat-load phase: 4 sequences per lane, 16B (1KB/wave) nt loads ----
    const int sbase = blockIdx.x * SEQS;      // block's first sequence
    const int tb    = w * CHUNK;              // wave's first time-step

    v4i pfA[CHUNK], pfB[CHUNK], idv[CHUNK];
#pragma unroll
    for (int k = 0; k < CHUNK; ++k) {
        const int e = (tb + k) * B + sbase;   // int2-element index
        pfA[k] = __builtin_nontemporal_load(
            ((const v4i*)perf) + (e >> 1) + 2 * lane);          // seqs 4l,4l+1
        pfB[k] = __builtin_nontemporal_load(
            ((const v4i*)perf) + (e >> 1) + 2 * lane + 1);      // seqs 4l+2,4l+3
        idv[k] = __builtin_nontemporal_load(
            ((const v4i*)obsids) + (e >> 2) + lane);            // 4 ids
    }
    const v4i pid4 = __builtin_nontemporal_load(
        ((const v4i*)predids) + (sbase >> 2) + lane);

    unsigned a0 = ~0u, b0 = 0u, a1 = ~0u, b1 = 0u;
    unsigned a2 = ~0u, b2 = 0u, a3 = ~0u, b3 = 0u;

#define STEP(px, py, idq, pidq, aA, bB)                                     \
    do {                                                                    \
        const unsigned Q_  = Qtab[(idq) * QS + (pidq)];                     \
        const unsigned A_  = ((px) != 0) ? Q_ : 0xFFFFFFFFu;                \
        const unsigned Bv_ = ((py) != 0) ? Q_ : 0u;                         \
        aA = aA & A_;                                                       \
        bB = (bB & A_) | Bv_;                                               \
    } while (0)

#pragma unroll
    for (int k = 0; k < CHUNK; ++k) {
        STEP(pfA[k].x, pfA[k].y, idv[k].x, pid4.x, a0, b0);
        STEP(pfA[k].z, pfA[k].w, idv[k].y, pid4.y, a1, b1);
        STEP(pfB[k].x, pfB[k].y, idv[k].z, pid4.z, a2, b2);
        STEP(pfB[k].z, pfB[k].w, idv[k].w, pid4.w, a3, b3);
    }
#undef STEP

    const int s0 = 4 * lane;
    sab[w][s0 + 0] = make_uint2(a0, b0);
    sab[w][s0 + 1] = make_uint2(a1, b1);
    sab[w][s0 + 2] = make_uint2(a2, b2);
    sab[w][s0 + 3] = make_uint2(a3, b3);
    __syncthreads();

    // ---- combine 8 chunks in t order; one thread per sequence ----
    if (tid < SEQS) {
        uint2 c0 = sab[0][tid];
        unsigned ca = c0.x, cb = c0.y;
#pragma unroll
        for (int wv = 1; wv < WAVES; ++wv) {
            const uint2 c2 = sab[wv][tid];
            cb = (cb & c2.x) | c2.y;
            ca = ca & c2.x;
        }
        const int pid = __builtin_nontemporal_load(predids + sbase + tid);
        const unsigned Winit = Qtab[6 * QS + pid];  // bit c = (M[c,pid] <= 0)
        const unsigned W = (Winit & ca) | cb;
        __builtin_nontemporal_store((W == 0xFFFFFFFFu) ? 1.0f : 0.0f,
                                    out + sbase + tid);
    }
}

}  // namespace

extern "C" void kernel_launch(void* const* d_in, const int* in_sizes, int n_in,
                              void* d_out, int out_size, void* d_ws, size_t ws_size,
                              hipStream_t stream) {
    const int2*  perf    = (const int2*)d_in[0];   // inptasksperf [T,B,2] int32
    const int*   obsids  = (const int*)d_in[1];    // tasksobsids  [T,B,1] int32
    const int*   predids = (const int*)d_in[2];    // taskspredids [B,1]   int32
    const float* obsM    = (const float*)d_in[3];  // obsMatrix    [C,NT]  f32
    float*       out     = (float*)d_out;          // trust        [B,1]   f32

    dim3 grid(B / SEQS), block(BLOCK);             // 256 blocks x 512 threads
    trust_kernel<<<grid, block, 0, stream>>>(perf, obsids, predids, obsM, out);
}

// Round 9
// 13.878 us; speedup vs baseline: 2.0135x; 1.0129x over previous
//
#include <hip/hip_runtime.h>

namespace {

constexpr int T = 64;
constexpr int B = 65536;
constexpr int C = 32;
constexpr int NT = 6;
constexpr int WAVES = 8;            // waves per block
constexpr int BLOCK = WAVES * 64;   // 512 threads
constexpr int CHUNK = T / WAVES;    // 8 time-steps per wave
constexpr int SEQS = 256;           // sequences per block (4 per lane)
constexpr int QS = 8;               // u32 stride per id-row of Q table

typedef int v4i __attribute__((ext_vector_type(4)));

#if __has_builtin(__builtin_amdgcn_make_buffer_rsrc) && \
    __has_builtin(__builtin_amdgcn_raw_buffer_load_b128)
#define USE_BUF 1
#else
#define USE_BUF 0
#endif

// Algebra (validated R3-R8): per sequence b with prediction column pid, track
// W (bit c = "M[c,pid] <= mean[c]"). Success id: W |= Q[id]; failure:
// W &= Q[id]; noop unchanged, where Q[id] bit c = (M[c,pid] <= M[c,id]).
// Steps are affine boolean maps W -> (W & A) | Bv, composing associatively.
//
// Loads use CPol NT|SC1 (0x12): the harness's per-replay 268MB fill leaves the
// 256MB Infinity Cache full of dirty lines; a read that allocates in MALL
// evicts a dirty line -> writeback on our critical path. NT alone (R8) fixed
// L2 allocation (16.1 -> 14.1us); NT|SC1 targets MALL allocation too.
__global__ __launch_bounds__(BLOCK) void trust_kernel(
    const int2* __restrict__ perf,    // [T*B] (x = failure, y = success)
    const int*  __restrict__ obsids,  // [T*B]
    const int*  __restrict__ predids, // [B]
    const float* __restrict__ obsM,   // [C*NT] row-major [C][NT]
    float* __restrict__ out)          // [B]
{
    __shared__ float    MT[NT * C];     // MT[j*32+c] = M[c][j]
    __shared__ unsigned Qtab[7 * QS];   // row id==6 encodes the t=0 state
    __shared__ uint2    sab[WAVES][SEQS];  // per-chunk (a,b) per sequence

    const int tid  = threadIdx.x;
    const int lane = tid & 63;
    const int w    = tid >> 6;

    // ---- prologue: build Q table (once), before load issue ----
    if (tid < C * NT) {
        const int c = tid / NT, j = tid - c * NT;
        MT[j * C + c] = obsM[tid];
    }
    __syncthreads();
    {
        const int half = lane >> 5;
        const int c    = lane & 31;
        for (int k = w; k <= 20; k += WAVES) {
            const int e   = 2 * k + half;     // entry 0..41
            const int id  = e / 6;
            const int pid = e - id * 6;
            const float val = (id < 6) ? MT[id * C + c] : 0.0f;  // id6 => mean=0
            const float req = MT[pid * C + c];
            const unsigned long long bal = __ballot(req <= val);
            if (c == 0) {
                Qtab[id * QS + pid] =
                    (unsigned)(half ? (bal >> 32) : (bal & 0xFFFFFFFFull));
            }
        }
    }
    __syncthreads();

    // ---- fat-load phase: 4 sequences per lane, 16B (1KB/wave) loads ----
    const int sbase = blockIdx.x * SEQS;      // block's first sequence
    const int tb    = w * CHUNK;              // wave's first time-step

    v4i pfA[CHUNK], pfB[CHUNK], idv[CHUNK];
#if USE_BUF
    const auto rs_perf = __builtin_amdgcn_make_buffer_rsrc(
        (void*)perf, (short)0, T * B * 8, 0x00020000);
    const auto rs_ids = __builtin_amdgcn_make_buffer_rsrc(
        (void*)obsids, (short)0, T * B * 4, 0x00020000);
    const auto rs_pid = __builtin_amdgcn_make_buffer_rsrc(
        (void*)predids, (short)0, B * 4, 0x00020000);
#pragma unroll
    for (int k = 0; k < CHUNK; ++k) {
        const int e = (tb + k) * B + sbase;   // int2-element index
        pfA[k] = (v4i)__builtin_amdgcn_raw_buffer_load_b128(
            rs_perf, e * 8 + 32 * lane, 0, 0x12);       // seqs 4l,4l+1
        pfB[k] = (v4i)__builtin_amdgcn_raw_buffer_load_b128(
            rs_perf, e * 8 + 32 * lane + 16, 0, 0x12);  // seqs 4l+2,4l+3
        idv[k] = (v4i)__builtin_amdgcn_raw_buffer_load_b128(
            rs_ids, e * 4 + 16 * lane, 0, 0x12);        // 4 ids
    }
    const v4i pid4 = (v4i)__builtin_amdgcn_raw_buffer_load_b128(
        rs_pid, sbase * 4 + 16 * lane, 0, 0x12);
#else
#pragma unroll
    for (int k = 0; k < CHUNK; ++k) {
        const int e = (tb + k) * B + sbase;
        pfA[k] = __builtin_nontemporal_load(((const v4i*)perf) + (e >> 1) + 2 * lane);
        pfB[k] = __builtin_nontemporal_load(((const v4i*)perf) + (e >> 1) + 2 * lane + 1);
        idv[k] = __builtin_nontemporal_load(((const v4i*)obsids) + (e >> 2) + lane);
    }
    const v4i pid4 = __builtin_nontemporal_load(
        ((const v4i*)predids) + (sbase >> 2) + lane);
#endif

    unsigned a0 = ~0u, b0 = 0u, a1 = ~0u, b1 = 0u;
    unsigned a2 = ~0u, b2 = 0u, a3 = ~0u, b3 = 0u;

#define STEP(px, py, idq, pidq, aA, bB)                                     \
    do {                                                                    \
        const unsigned Q_  = Qtab[(idq) * QS + (pidq)];                     \
        const unsigned A_  = ((px) != 0) ? Q_ : 0xFFFFFFFFu;                \
        const unsigned Bv_ = ((py) != 0) ? Q_ : 0u;                         \
        aA = aA & A_;                                                       \
        bB = (bB & A_) | Bv_;                                               \
    } while (0)

#pragma unroll
    for (int k = 0; k < CHUNK; ++k) {
        STEP(pfA[k].x, pfA[k].y, idv[k].x, pid4.x, a0, b0);
        STEP(pfA[k].z, pfA[k].w, idv[k].y, pid4.y, a1, b1);
        STEP(pfB[k].x, pfB[k].y, idv[k].z, pid4.z, a2, b2);
        STEP(pfB[k].z, pfB[k].w, idv[k].w, pid4.w, a3, b3);
    }
#undef STEP

    const int s0 = 4 * lane;
    sab[w][s0 + 0] = make_uint2(a0, b0);
    sab[w][s0 + 1] = make_uint2(a1, b1);
    sab[w][s0 + 2] = make_uint2(a2, b2);
    sab[w][s0 + 3] = make_uint2(a3, b3);
    __syncthreads();

    // ---- combine 8 chunks in t order; one thread per sequence ----
    if (tid < SEQS) {
        uint2 c0 = sab[0][tid];
        unsigned ca = c0.x, cb = c0.y;
#pragma unroll
        for (int wv = 1; wv < WAVES; ++wv) {
            const uint2 c2 = sab[wv][tid];
            cb = (cb & c2.x) | c2.y;
            ca = ca & c2.x;
        }
        const int pid = __builtin_nontemporal_load(predids + sbase + tid);
        const unsigned Winit = Qtab[6 * QS + pid];  // bit c = (M[c,pid] <= 0)
        const unsigned W = (Winit & ca) | cb;
        __builtin_nontemporal_store((W == 0xFFFFFFFFu) ? 1.0f : 0.0f,
                                    out + sbase + tid);
    }
}

}  // namespace

extern "C" void kernel_launch(void* const* d_in, const int* in_sizes, int n_in,
                              void* d_out, int out_size, void* d_ws, size_t ws_size,
                              hipStream_t stream) {
    const int2*  perf    = (const int2*)d_in[0];   // inptasksperf [T,B,2] int32
    const int*   obsids  = (const int*)d_in[1];    // tasksobsids  [T,B,1] int32
    const int*   predids = (const int*)d_in[2];    // taskspredids [B,1]   int32
    const float* obsM    = (const float*)d_in[3];  // obsMatrix    [C,NT]  f32
    float*       out     = (float*)d_out;          // trust        [B,1]   f32

    dim3 grid(B / SEQS), block(BLOCK);             // 256 blocks x 512 threads
    trust_kernel<<<grid, block, 0, stream>>>(perf, obsids, predids, obsM, out);
}

// Round 10
// 12.152 us; speedup vs baseline: 2.2995x; 1.1420x over previous
//
#include <hip/hip_runtime.h>

namespace {

constexpr int T = 64;
constexpr int B = 65536;
constexpr int C = 32;
constexpr int NT = 6;
constexpr int WAVES = 8;            // waves per block
constexpr int BLOCK = WAVES * 64;   // 512 threads
constexpr int CHUNK = T / WAVES;    // 8 time-steps per wave
constexpr int SEQS = 128;           // sequences per block (2 per lane) -> 2 blocks/CU
constexpr int QS = 8;               // u32 stride per id-row of Q table

typedef int v4i __attribute__((ext_vector_type(4)));
typedef int v2i __attribute__((ext_vector_type(2)));

#if __has_builtin(__builtin_amdgcn_make_buffer_rsrc) &&   \
    __has_builtin(__builtin_amdgcn_raw_buffer_load_b128) && \
    __has_builtin(__builtin_amdgcn_raw_buffer_load_b64)
#define USE_BUF 1
#else
#define USE_BUF 0
#endif

// Algebra (validated R3-R9): per sequence b with prediction column pid, track
// W (bit c = "M[c,pid] <= mean[c]"). Success id: W |= Q[id]; failure:
// W &= Q[id]; noop unchanged, where Q[id] bit c = (M[c,pid] <= M[c,id]).
// Steps are affine boolean maps W -> (W & A) | Bv, composing associatively.
//
// Phase order: issue ALL streaming loads first (nt, CPol 0x12), THEN build the
// Q table while they are in flight, then fold. 2 blocks/CU so one block's
// compute/combine overlaps the other's memory phase.
__global__ __launch_bounds__(BLOCK) void trust_kernel(
    const int2* __restrict__ perf,    // [T*B] (x = failure, y = success)
    const int*  __restrict__ obsids,  // [T*B]
    const int*  __restrict__ predids, // [B]
    const float* __restrict__ obsM,   // [C*NT] row-major [C][NT]
    float* __restrict__ out)          // [B]
{
    __shared__ float    MT[NT * C];     // MT[j*32+c] = M[c][j]
    __shared__ unsigned Qtab[7 * QS];   // row id==6 encodes the t=0 state
    __shared__ uint2    sab[WAVES][SEQS];  // per-chunk (a,b) per sequence

    const int tid  = threadIdx.x;
    const int lane = tid & 63;
    const int w    = tid >> 6;

    const int sbase = blockIdx.x * SEQS;  // block's first sequence
    const int tb    = w * CHUNK;          // wave's first time-step

    // ---- issue streaming loads FIRST (2 seqs/lane, nt) ----
    v4i pf2[CHUNK];   // perf for 2 seqs (2 x int2)
    v2i idv[CHUNK];   // ids  for 2 seqs
#if USE_BUF
    const auto rs_perf = __builtin_amdgcn_make_buffer_rsrc(
        (void*)perf, (short)0, T * B * 8, 0x00020000);
    const auto rs_ids = __builtin_amdgcn_make_buffer_rsrc(
        (void*)obsids, (short)0, T * B * 4, 0x00020000);
    const auto rs_pid = __builtin_amdgcn_make_buffer_rsrc(
        (void*)predids, (short)0, B * 4, 0x00020000);
#pragma unroll
    for (int k = 0; k < CHUNK; ++k) {
        const int e = (tb + k) * B + sbase;   // int2-element index
        pf2[k] = (v4i)__builtin_amdgcn_raw_buffer_load_b128(
            rs_perf, e * 8 + 16 * lane, 0, 0x12);   // seqs 2l, 2l+1
        idv[k] = (v2i)__builtin_amdgcn_raw_buffer_load_b64(
            rs_ids, e * 4 + 8 * lane, 0, 0x12);     // 2 ids
    }
    const v2i pid2 = (v2i)__builtin_amdgcn_raw_buffer_load_b64(
        rs_pid, sbase * 4 + 8 * lane, 0, 0x12);
#else
#pragma unroll
    for (int k = 0; k < CHUNK; ++k) {
        const int e = (tb + k) * B + sbase;
        pf2[k] = __builtin_nontemporal_load(((const v4i*)perf) + (e >> 1) + lane);
        idv[k] = __builtin_nontemporal_load(((const v2i*)obsids) + (e >> 1) + lane);
    }
    const v2i pid2 = __builtin_nontemporal_load(
        ((const v2i*)predids) + (sbase >> 1) + lane);
#endif

    // ---- Q-table build (hidden under the in-flight loads) ----
    if (tid < C * NT) {
        const int c = tid / NT, j = tid - c * NT;
        MT[j * C + c] = obsM[tid];
    }
    __syncthreads();
    {
        const int half = lane >> 5;
        const int c    = lane & 31;
        for (int k = w; k <= 20; k += WAVES) {
            const int e   = 2 * k + half;     // entry 0..41
            const int id  = e / 6;
            const int pid = e - id * 6;
            const float val = (id < 6) ? MT[id * C + c] : 0.0f;  // id6 => mean=0
            const float req = MT[pid * C + c];
            const unsigned long long bal = __ballot(req <= val);
            if (c == 0) {
                Qtab[id * QS + pid] =
                    (unsigned)(half ? (bal >> 32) : (bal & 0xFFFFFFFFull));
            }
        }
    }
    __syncthreads();

    // ---- fold: 2 sequences per lane ----
    unsigned a0 = ~0u, b0 = 0u, a1 = ~0u, b1 = 0u;

#define STEP(px, py, idq, pidq, aA, bB)                                     \
    do {                                                                    \
        const unsigned Q_  = Qtab[(idq) * QS + (pidq)];                     \
        const unsigned A_  = ((px) != 0) ? Q_ : 0xFFFFFFFFu;                \
        const unsigned Bv_ = ((py) != 0) ? Q_ : 0u;                         \
        aA = aA & A_;                                                       \
        bB = (bB & A_) | Bv_;                                               \
    } while (0)

#pragma unroll
    for (int k = 0; k < CHUNK; ++k) {
        STEP(pf2[k].x, pf2[k].y, idv[k].x, pid2.x, a0, b0);
        STEP(pf2[k].z, pf2[k].w, idv[k].y, pid2.y, a1, b1);
    }
#undef STEP

    const int s0 = 2 * lane;
    sab[w][s0 + 0] = make_uint2(a0, b0);
    sab[w][s0 + 1] = make_uint2(a1, b1);
    __syncthreads();

    // ---- combine 8 chunks in t order; one thread per sequence ----
    if (tid < SEQS) {
        uint2 c0 = sab[0][tid];
        unsigned ca = c0.x, cb = c0.y;
#pragma unroll
        for (int wv = 1; wv < WAVES; ++wv) {
            const uint2 c2 = sab[wv][tid];
            cb = (cb & c2.x) | c2.y;
            ca = ca & c2.x;
        }
        const int pid = __builtin_nontemporal_load(predids + sbase + tid);
        const unsigned Winit = Qtab[6 * QS + pid];  // bit c = (M[c,pid] <= 0)
        const unsigned W = (Winit & ca) | cb;
        __builtin_nontemporal_store((W == 0xFFFFFFFFu) ? 1.0f : 0.0f,
                                    out + sbase + tid);
    }
}

}  // namespace

extern "C" void kernel_launch(void* const* d_in, const int* in_sizes, int n_in,
                              void* d_out, int out_size, void* d_ws, size_t ws_size,
                              hipStream_t stream) {
    const int2*  perf    = (const int2*)d_in[0];   // inptasksperf [T,B,2] int32
    const int*   obsids  = (const int*)d_in[1];    // tasksobsids  [T,B,1] int32
    const int*   predids = (const int*)d_in[2];    // taskspredids [B,1]   int32
    const float* obsM    = (const float*)d_in[3];  // obsMatrix    [C,NT]  f32
    float*       out     = (float*)d_out;          // trust        [B,1]   f32

    dim3 grid(B / SEQS), block(BLOCK);             // 512 blocks x 512 threads
    trust_kernel<<<grid, block, 0, stream>>>(perf, obsids, predids, obsM, out);
}

// Round 11
// 12.143 us; speedup vs baseline: 2.3011x; 1.0007x over previous
//
#include <hip/hip_runtime.h>

namespace {

constexpr int T = 64;
constexpr int B = 65536;
constexpr int C = 32;
constexpr int NT = 6;
constexpr int WAVES = 16;           // waves per block
constexpr int BLOCK = WAVES * 64;   // 1024 threads
constexpr int CHUNK = T / WAVES;    // 4 time-steps per wave
constexpr int SEQS = 128;           // sequences per block (2 per lane)
constexpr int QS = 8;               // u32 stride per id-row of Q table

typedef int v4i __attribute__((ext_vector_type(4)));
typedef int v2i __attribute__((ext_vector_type(2)));

#if __has_builtin(__builtin_amdgcn_make_buffer_rsrc) &&   \
    __has_builtin(__builtin_amdgcn_raw_buffer_load_b128) && \
    __has_builtin(__builtin_amdgcn_raw_buffer_load_b64)
#define USE_BUF 1
#else
#define USE_BUF 0
#endif

// Algebra (validated R3-R10): per sequence b with prediction column pid, track
// W (bit c = "M[c,pid] <= mean[c]"). Success id: W |= Q[id]; failure:
// W &= Q[id]; noop unchanged, where Q[id] bit c = (M[c,pid] <= M[c,id]).
// Steps are affine boolean maps W -> (W & A) | Bv, composing associatively.
//
// Schedule (validated R10): issue ALL streaming loads first (nt, CPol 0x12 -
// the harness's per-replay 268MB fill leaves L3 full of dirty lines; allocating
// reads would trigger writeback-per-read), hide the Q-table build under them.
// R11: 16 waves x CHUNK=4 -> 32 waves/CU (max occupancy), halved per-wave
// critical path, same 1KB/512B wave-request widths.
__global__ __launch_bounds__(BLOCK) void trust_kernel(
    const int2* __restrict__ perf,    // [T*B] (x = failure, y = success)
    const int*  __restrict__ obsids,  // [T*B]
    const int*  __restrict__ predids, // [B]
    const float* __restrict__ obsM,   // [C*NT] row-major [C][NT]
    float* __restrict__ out)          // [B]
{
    __shared__ float    MT[NT * C];     // MT[j*32+c] = M[c][j]
    __shared__ unsigned Qtab[7 * QS];   // row id==6 encodes the t=0 state
    __shared__ uint2    sab[WAVES][SEQS];  // per-chunk (a,b) per sequence

    const int tid  = threadIdx.x;
    const int lane = tid & 63;
    const int w    = tid >> 6;

    const int sbase = blockIdx.x * SEQS;  // block's first sequence
    const int tb    = w * CHUNK;          // wave's first time-step

    // ---- issue streaming loads FIRST (2 seqs/lane, nt) ----
    v4i pf2[CHUNK];   // perf for 2 seqs (2 x int2)
    v2i idv[CHUNK];   // ids  for 2 seqs
#if USE_BUF
    const auto rs_perf = __builtin_amdgcn_make_buffer_rsrc(
        (void*)perf, (short)0, T * B * 8, 0x00020000);
    const auto rs_ids = __builtin_amdgcn_make_buffer_rsrc(
        (void*)obsids, (short)0, T * B * 4, 0x00020000);
    const auto rs_pid = __builtin_amdgcn_make_buffer_rsrc(
        (void*)predids, (short)0, B * 4, 0x00020000);
#pragma unroll
    for (int k = 0; k < CHUNK; ++k) {
        const int e = (tb + k) * B + sbase;   // int2-element index
        pf2[k] = (v4i)__builtin_amdgcn_raw_buffer_load_b128(
            rs_perf, e * 8 + 16 * lane, 0, 0x12);   // seqs 2l, 2l+1
        idv[k] = (v2i)__builtin_amdgcn_raw_buffer_load_b64(
            rs_ids, e * 4 + 8 * lane, 0, 0x12);     // 2 ids
    }
    const v2i pid2 = (v2i)__builtin_amdgcn_raw_buffer_load_b64(
        rs_pid, sbase * 4 + 8 * lane, 0, 0x12);
#else
#pragma unroll
    for (int k = 0; k < CHUNK; ++k) {
        const int e = (tb + k) * B + sbase;
        pf2[k] = __builtin_nontemporal_load(((const v4i*)perf) + (e >> 1) + lane);
        idv[k] = __builtin_nontemporal_load(((const v2i*)obsids) + (e >> 1) + lane);
    }
    const v2i pid2 = __builtin_nontemporal_load(
        ((const v2i*)predids) + (sbase >> 1) + lane);
#endif

    // ---- Q-table build (hidden under the in-flight loads) ----
    if (tid < C * NT) {
        const int c = tid / NT, j = tid - c * NT;
        MT[j * C + c] = obsM[tid];
    }
    __syncthreads();
    {
        const int half = lane >> 5;
        const int c    = lane & 31;
        for (int k = w; k <= 20; k += WAVES) {
            const int e   = 2 * k + half;     // entry 0..41
            const int id  = e / 6;
            const int pid = e - id * 6;
            const float val = (id < 6) ? MT[id * C + c] : 0.0f;  // id6 => mean=0
            const float req = MT[pid * C + c];
            const unsigned long long bal = __ballot(req <= val);
            if (c == 0) {
                Qtab[id * QS + pid] =
                    (unsigned)(half ? (bal >> 32) : (bal & 0xFFFFFFFFull));
            }
        }
    }
    __syncthreads();

    // ---- fold: 2 sequences per lane, 4 steps ----
    unsigned a0 = ~0u, b0 = 0u, a1 = ~0u, b1 = 0u;

#define STEP(px, py, idq, pidq, aA, bB)                                     \
    do {                                                                    \
        const unsigned Q_  = Qtab[(idq) * QS + (pidq)];                     \
        const unsigned A_  = ((px) != 0) ? Q_ : 0xFFFFFFFFu;                \
        const unsigned Bv_ = ((py) != 0) ? Q_ : 0u;                         \
        aA = aA & A_;                                                       \
        bB = (bB & A_) | Bv_;                                               \
    } while (0)

#pragma unroll
    for (int k = 0; k < CHUNK; ++k) {
        STEP(pf2[k].x, pf2[k].y, idv[k].x, pid2.x, a0, b0);
        STEP(pf2[k].z, pf2[k].w, idv[k].y, pid2.y, a1, b1);
    }
#undef STEP

    const int s0 = 2 * lane;
    sab[w][s0 + 0] = make_uint2(a0, b0);
    sab[w][s0 + 1] = make_uint2(a1, b1);
    __syncthreads();

    // ---- combine 16 chunks in t order; one thread per sequence ----
    if (tid < SEQS) {
        uint2 c0 = sab[0][tid];
        unsigned ca = c0.x, cb = c0.y;
#pragma unroll
        for (int wv = 1; wv < WAVES; ++wv) {
            const uint2 c2 = sab[wv][tid];
            cb = (cb & c2.x) | c2.y;
            ca = ca & c2.x;
        }
        const int pid = __builtin_nontemporal_load(predids + sbase + tid);
        const unsigned Winit = Qtab[6 * QS + pid];  // bit c = (M[c,pid] <= 0)
        const unsigned W = (Winit & ca) | cb;
        __builtin_nontemporal_store((W == 0xFFFFFFFFu) ? 1.0f : 0.0f,
                                    out + sbase + tid);
    }
}

}  // namespace

extern "C" void kernel_launch(void* const* d_in, const int* in_sizes, int n_in,
                              void* d_out, int out_size, void* d_ws, size_t ws_size,
                              hipStream_t stream) {
    const int2*  perf    = (const int2*)d_in[0];   // inptasksperf [T,B,2] int32
    const int*   obsids  = (const int*)d_in[1];    // tasksobsids  [T,B,1] int32
    const int*   predids = (const int*)d_in[2];    // taskspredids [B,1]   int32
    const float* obsM    = (const float*)d_in[3];  // obsMatrix    [C,NT]  f32
    float*       out     = (float*)d_out;          // trust        [B,1]   f32

    dim3 grid(B / SEQS), block(BLOCK);             // 512 blocks x 1024 threads
    trust_kernel<<<grid, block, 0, stream>>>(perf, obsids, predids, obsM, out);
}

// Round 12
// 12.136 us; speedup vs baseline: 2.3025x; 1.0006x over previous
//
#include <hip/hip_runtime.h>

namespace {

constexpr int T = 64;
constexpr int B = 65536;
constexpr int C = 32;
constexpr int NT = 6;
constexpr int WAVES = 16;           // waves per block
constexpr int BLOCK = WAVES * 64;   // 1024 threads
constexpr int CHUNK = T / WAVES;    // 4 time-steps per wave
constexpr int SEQS = 128;           // sequences per block (2 per lane)
constexpr int QS = 8;               // u32 stride per id-row of Q table

typedef int v4i __attribute__((ext_vector_type(4)));
typedef int v2i __attribute__((ext_vector_type(2)));

#if __has_builtin(__builtin_amdgcn_make_buffer_rsrc) &&   \
    __has_builtin(__builtin_amdgcn_raw_buffer_load_b128) && \
    __has_builtin(__builtin_amdgcn_raw_buffer_load_b64)
#define USE_BUF 1
#else
#define USE_BUF 0
#endif

// CPol 0x2 = NT only (device scope). R8 showed NT avoids the L3-dirty-line
// eviction storm from the harness's per-replay 268MB fill (16.1 -> 14.1us).
// R12 drops SC1 (system scope) in case its coherent path throttles read BW.
constexpr int CPOL = 0x2;

// Algebra (validated R3-R11): per sequence b with prediction column pid, track
// W (bit c = "M[c,pid] <= mean[c]"). Success id: W |= Q[id]; failure:
// W &= Q[id]; noop unchanged, where Q[id] bit c = (M[c,pid] <= M[c,id]).
// Steps are affine boolean maps W -> (W & A) | Bv, composing associatively.
// Schedule (validated R10): all streaming loads issue first; Q-table build
// hides under them; 32 waves/CU.
__global__ __launch_bounds__(BLOCK) void trust_kernel(
    const int2* __restrict__ perf,    // [T*B] (x = failure, y = success)
    const int*  __restrict__ obsids,  // [T*B]
    const int*  __restrict__ predids, // [B]
    const float* __restrict__ obsM,   // [C*NT] row-major [C][NT]
    float* __restrict__ out)          // [B]
{
    __shared__ float    MT[NT * C];     // MT[j*32+c] = M[c][j]
    __shared__ unsigned Qtab[7 * QS];   // row id==6 encodes the t=0 state
    __shared__ uint2    sab[WAVES][SEQS];  // per-chunk (a,b) per sequence

    const int tid  = threadIdx.x;
    const int lane = tid & 63;
    const int w    = tid >> 6;

    const int sbase = blockIdx.x * SEQS;  // block's first sequence
    const int tb    = w * CHUNK;          // wave's first time-step

    // ---- issue streaming loads FIRST (2 seqs/lane, nt) ----
    v4i pf2[CHUNK];   // perf for 2 seqs (2 x int2)
    v2i idv[CHUNK];   // ids  for 2 seqs
#if USE_BUF
    const auto rs_perf = __builtin_amdgcn_make_buffer_rsrc(
        (void*)perf, (short)0, T * B * 8, 0x00020000);
    const auto rs_ids = __builtin_amdgcn_make_buffer_rsrc(
        (void*)obsids, (short)0, T * B * 4, 0x00020000);
    const auto rs_pid = __builtin_amdgcn_make_buffer_rsrc(
        (void*)predids, (short)0, B * 4, 0x00020000);
#pragma unroll
    for (int k = 0; k < CHUNK; ++k) {
        const int e = (tb + k) * B + sbase;   // int2-element index
        pf2[k] = (v4i)__builtin_amdgcn_raw_buffer_load_b128(
            rs_perf, e * 8 + 16 * lane, 0, CPOL);   // seqs 2l, 2l+1
        idv[k] = (v2i)__builtin_amdgcn_raw_buffer_load_b64(
            rs_ids, e * 4 + 8 * lane, 0, CPOL);     // 2 ids
    }
    const v2i pid2 = (v2i)__builtin_amdgcn_raw_buffer_load_b64(
        rs_pid, sbase * 4 + 8 * lane, 0, CPOL);
#else
#pragma unroll
    for (int k = 0; k < CHUNK; ++k) {
        const int e = (tb + k) * B + sbase;
        pf2[k] = __builtin_nontemporal_load(((const v4i*)perf) + (e >> 1) + lane);
        idv[k] = __builtin_nontemporal_load(((const v2i*)obsids) + (e >> 1) + lane);
    }
    const v2i pid2 = __builtin_nontemporal_load(
        ((const v2i*)predids) + (sbase >> 1) + lane);
#endif

    // ---- Q-table build (hidden under the in-flight loads) ----
    if (tid < C * NT) {
        const int c = tid / NT, j = tid - c * NT;
        MT[j * C + c] = obsM[tid];
    }
    __syncthreads();
    {
        const int half = lane >> 5;
        const int c    = lane & 31;
        for (int k = w; k <= 20; k += WAVES) {
            const int e   = 2 * k + half;     // entry 0..41
            const int id  = e / 6;
            const int pid = e - id * 6;
            const float val = (id < 6) ? MT[id * C + c] : 0.0f;  // id6 => mean=0
            const float req = MT[pid * C + c];
            const unsigned long long bal = __ballot(req <= val);
            if (c == 0) {
                Qtab[id * QS + pid] =
                    (unsigned)(half ? (bal >> 32) : (bal & 0xFFFFFFFFull));
            }
        }
    }
    __syncthreads();

    // ---- fold: 2 sequences per lane, 4 steps ----
    unsigned a0 = ~0u, b0 = 0u, a1 = ~0u, b1 = 0u;

#define STEP(px, py, idq, pidq, aA, bB)                                     \
    do {                                                                    \
        const unsigned Q_  = Qtab[(idq) * QS + (pidq)];                     \
        const unsigned A_  = ((px) != 0) ? Q_ : 0xFFFFFFFFu;                \
        const unsigned Bv_ = ((py) != 0) ? Q_ : 0u;                         \
        aA = aA & A_;                                                       \
        bB = (bB & A_) | Bv_;                                               \
    } while (0)

#pragma unroll
    for (int k = 0; k < CHUNK; ++k) {
        STEP(pf2[k].x, pf2[k].y, idv[k].x, pid2.x, a0, b0);
        STEP(pf2[k].z, pf2[k].w, idv[k].y, pid2.y, a1, b1);
    }
#undef STEP

    const int s0 = 2 * lane;
    sab[w][s0 + 0] = make_uint2(a0, b0);
    sab[w][s0 + 1] = make_uint2(a1, b1);
    __syncthreads();

    // ---- combine 16 chunks in t order; one thread per sequence ----
    if (tid < SEQS) {
        uint2 c0 = sab[0][tid];
        unsigned ca = c0.x, cb = c0.y;
#pragma unroll
        for (int wv = 1; wv < WAVES; ++wv) {
            const uint2 c2 = sab[wv][tid];
            cb = (cb & c2.x) | c2.y;
            ca = ca & c2.x;
        }
        const int pid = __builtin_nontemporal_load(predids + sbase + tid);
        const unsigned Winit = Qtab[6 * QS + pid];  // bit c = (M[c,pid] <= 0)
        const unsigned W = (Winit & ca) | cb;
        __builtin_nontemporal_store((W == 0xFFFFFFFFu) ? 1.0f : 0.0f,
                                    out + sbase + tid);
    }
}

}  // namespace

extern "C" void kernel_launch(void* const* d_in, const int* in_sizes, int n_in,
                              void* d_out, int out_size, void* d_ws, size_t ws_size,
                              hipStream_t stream) {
    const int2*  perf    = (const int2*)d_in[0];   // inptasksperf [T,B,2] int32
    const int*   obsids  = (const int*)d_in[1];    // tasksobsids  [T,B,1] int32
    const int*   predids = (const int*)d_in[2];    // taskspredids [B,1]   int32
    const float* obsM    = (const float*)d_in[3];  // obsMatrix    [C,NT]  f32
    float*       out     = (float*)d_out;          // trust        [B,1]   f32

    dim3 grid(B / SEQS), block(BLOCK);             // 512 blocks x 1024 threads
    trust_kernel<<<grid, block, 0, stream>>>(perf, obsids, predids, obsM, out);
}